// Round 11
// baseline (154.220 us; speedup 1.0000x reference)
//
#include <hip/hip_runtime.h>
#include <hip/hip_bf16.h>

#define HH 128
#define WW 128
#define CC 64
#define TT 5
#define HW (HH*WW)
#define NI 10

typedef __attribute__((ext_vector_type(8))) short short8;
typedef __attribute__((ext_vector_type(4))) float f32x4;

typedef const unsigned int __attribute__((address_space(1))) gu32;
typedef unsigned int __attribute__((address_space(3))) lu32;

__device__ __forceinline__ void gl_lds16(const void* g, void* l) {
  __builtin_amdgcn_global_load_lds((gu32*)g, (lu32*)l, 16, 0, 0);
}

__device__ __forceinline__ float bf2f(unsigned int bits16) {
  union { unsigned int u; float f; } v; v.u = bits16 << 16; return v.f;
}
__device__ __forceinline__ unsigned short f2bf(float f) {
  __hip_bfloat16 h = __float2bfloat16(f);
  return *reinterpret_cast<unsigned short*>(&h);
}

// xb layout: 8-channel planes. Element (n, cg, p, c) at ((n*8+cg)*HW + p)*8 + c.
//
// R23 = R22 with the nontemporal-store compile fix (pack uint2 into a u64
// scalar; clang's builtin rejects HIP_vector_type). Theory unchanged:
// conv1 is L2-miss-traffic bound; nt-load x (pack) + nt-store yb (conv1)
// keeps the per-XCD xb slice L2-resident from pack through conv1.

// ---- merged pack (R20 swizzle; x reads non-temporal)
__global__ __launch_bounds__(256) void pack_k(const float* __restrict__ x,
    const float* __restrict__ w1, const float* __restrict__ w2,
    unsigned short* __restrict__ xb, unsigned short* __restrict__ wb1,
    unsigned short* __restrict__ wb2) {
  __shared__ unsigned short tb[128*68];
  const int tid = threadIdx.x;
  const int bx = blockIdx.x;
  if (bx >= NI*HH) {
    int idx = (bx - NI*HH)*256 + tid;
    if (idx < 64*576) {
      int oc = idx / 576, rem = idx - oc*576, kk = rem >> 6, ic = rem & 63;
      wb1[idx] = f2bf(w1[(oc*64 + ic)*9 + kk]);
    }
    if (idx < 16*576) {
      int oc = idx / 576, rem = idx - oc*576, kk = rem >> 6, ic = rem & 63;
      wb2[idx] = (oc < 9) ? f2bf(w2[(oc*64 + ic)*9 + kk]) : (unsigned short)0;
    }
    return;
  }
  // 1280 = 8*160; XCD (bx&7) owns items [k*160,(k+1)*160) = 1.25 frames
  const int item = (bx & 7)*160 + (bx >> 3);
  const int n = item >> 7, h = item & 127;
  const int bi = n / 5, ti = n - bi*5;
  const float* xp = x + ((size_t)bi*CC*TT + ti)*HW + (size_t)h*WW;
  for (int e = tid; e < 64*128; e += 256) {
    int ci = e >> 7, w = e & 127;
    // nt: x is use-once; keep it from evicting xb out of L2.
    tb[w*68 + ci] = f2bf(__builtin_nontemporal_load(&xp[(size_t)ci*TT*HW + w]));
  }
  __syncthreads();
  for (int e = tid; e < 1024; e += 256) {
    int w = e >> 3, cg = e & 7;
    uint2 lo = *(const uint2*)(&tb[w*68 + cg*8]);
    uint2 hi = *(const uint2*)(&tb[w*68 + cg*8 + 4]);
    uint4 v; v.x = lo.x; v.y = lo.y; v.z = hi.x; v.w = hi.y;
    *(uint4*)(xb + (((size_t)(n*8 + cg))*HW + (size_t)h*WW + w)*8) = v;
  }
}

// ---- conv1 v12: v10 body + XCD-chunked grid + nt yb stores.
#define STAGE_W1(OCBASE) do {                                               \
    _Pragma("unroll")                                                       \
    for (int it = 0; it < 9; ++it) {                                        \
      int e = tid + it*256;                                                 \
      int frag = e >> 6, ln = e & 63;                                       \
      int kk = frag >> 2, rem2 = frag & 3, half = rem2 >> 1, g = rem2 & 1;  \
      const unsigned short* src = wb1 + (size_t)((OCBASE) + g*16 + (ln & 15))*576 \
                                  + kk*64 + half*32 + ((ln >> 4) << 3);     \
      gl_lds16(src, (char*)wt + ((size_t)(it*256 + wbase) << 4));           \
    }                                                                       \
  } while (0)

__global__ __launch_bounds__(256, 3) void conv1_mfma(
    const unsigned short* __restrict__ xb, const unsigned short* __restrict__ wb1,
    const float* __restrict__ b1, unsigned short* __restrict__ yb) {
  __shared__ unsigned short wt[36*512];   // 36864 B
  const int tid = threadIdx.x;
  const int wave = tid >> 6, lane = tid & 63, q = lane >> 4, r = lane & 15;
  // 640 = 8*80; XCD (gid&7) owns items [k*80,(k+1)*80) = 1.25 frames
  const int item = (blockIdx.x & 7)*80 + (blockIdx.x >> 3);
  const int n = item >> 6;
  const int rem = item & 63;
  const int tyi = rem >> 3, txi = rem & 7;
  const int h0 = tyi << 4, w0 = txi << 4;
  const int wbase = tid & ~63;
  const bool interior = (txi >= 1) & (txi <= 6) & (tyi >= 1) & (tyi <= 6);

  STAGE_W1(0);
  __syncthreads();

  f32x4 zero4 = {0.f, 0.f, 0.f, 0.f};

  #pragma unroll
  for (int g2 = 0; g2 < 2; ++g2) {
    f32x4 acc[4][2];
    #pragma unroll
    for (int i = 0; i < 4; ++i)
      #pragma unroll
      for (int g = 0; g < 2; ++g) acc[i][g] = zero4;

    #pragma unroll
    for (int half = 0; half < 2; ++half) {
      short8 bf[6][3];
      if (interior) {
        #pragma unroll
        for (int rr = 0; rr < 6; ++rr) {
          const int gh = h0 + (wave << 2) + rr - 1;
          #pragma unroll
          for (int dx = 0; dx < 3; ++dx) {
            const int gw = w0 + r + dx - 1;
            const int cg = (half << 2) | q;
            bf[rr][dx] = *(const short8*)(xb +
                (((size_t)((n << 3) + cg))*HW + gh*WW + gw)*8);
          }
        }
      } else {
        #pragma unroll
        for (int rr = 0; rr < 6; ++rr) {
          const int gh = h0 + (wave << 2) + rr - 1;
          #pragma unroll
          for (int dx = 0; dx < 3; ++dx) {
            const int gw = w0 + r + dx - 1;
            const int cg = (half << 2) | q;
            const bool ok = ((unsigned)gh < (unsigned)HH) &
                            ((unsigned)gw < (unsigned)WW);
            const size_t off = ok ? (size_t)(gh*WW + gw) : (size_t)0;
            uint4 v = *(const uint4*)(xb +
                (((size_t)((n << 3) + cg))*HW + off)*8);
            if (!ok) v = make_uint4(0u, 0u, 0u, 0u);
            bf[rr][dx] = *reinterpret_cast<short8*>(&v);
          }
        }
      }
      #pragma unroll
      for (int kk = 0; kk < 9; ++kk) {
        const int dy = kk / 3, dx = kk - dy*3;
        short8 a0 = *(const short8*)(&wt[((kk*4 + half*2 + 0) << 9) + (lane << 3)]);
        short8 a1 = *(const short8*)(&wt[((kk*4 + half*2 + 1) << 9) + (lane << 3)]);
        #pragma unroll
        for (int i = 0; i < 4; ++i) {
          acc[i][0] = __builtin_amdgcn_mfma_f32_16x16x32_bf16(a0, bf[i+dy][dx], acc[i][0], 0, 0, 0);
          acc[i][1] = __builtin_amdgcn_mfma_f32_16x16x32_bf16(a1, bf[i+dy][dx], acc[i][1], 0, 0, 0);
        }
      }
    }

    if (g2 == 0) {
      __syncthreads();      // all waves done reading wt(group 0)
      STAGE_W1(32);         // stage oc 32..63; latency hidden under y-stores
    }

    #pragma unroll
    for (int i = 0; i < 4; ++i) {
      int py = wave*4 + i;
      unsigned short* yp = yb + ((size_t)n*HW + (h0+py)*WW + (w0+r))*64;
      #pragma unroll
      for (int g = 0; g < 2; ++g) {
        int oc0 = (g2 << 5) + g*16 + (q << 2);
        f32x4 bias = *(const f32x4*)(b1 + oc0);
        float v0 = acc[i][g][0] + bias[0]; v0 = (v0 >= 0.f) ? v0 : 0.2f*v0;
        float v1 = acc[i][g][1] + bias[1]; v1 = (v1 >= 0.f) ? v1 : 0.2f*v1;
        float v2 = acc[i][g][2] + bias[2]; v2 = (v2 >= 0.f) ? v2 : 0.2f*v2;
        float v3 = acc[i][g][3] + bias[3]; v3 = (v3 >= 0.f) ? v3 : 0.2f*v3;
        unsigned long long pk =
            (unsigned long long)((unsigned int)f2bf(v0) |
                                 ((unsigned int)f2bf(v1) << 16)) |
            ((unsigned long long)((unsigned int)f2bf(v2) |
                                  ((unsigned int)f2bf(v3) << 16)) << 32);
        // nt: yb is consumed by conv2 from L3; don't let it evict xb from L2.
        __builtin_nontemporal_store(pk, (unsigned long long*)(yp + oc0));
      }
    }

    if (g2 == 0) __syncthreads();   // wt(group 1) landed
  }
}

// ---- conv2 v7 (R20: XCD-swizzled 1D grid of 1280)
__global__ __launch_bounds__(256) void conv2_mfma(
    const unsigned short* __restrict__ yb, const unsigned short* __restrict__ wb2,
    const float* __restrict__ b2, float* __restrict__ ker0) {
  __shared__ unsigned short yt[180*64];
  __shared__ unsigned short wt[18*512];
  const int tid = threadIdx.x;
  const int wave = tid >> 6, lane = tid & 63, q = lane >> 4, r = lane & 15;
  const int item = (blockIdx.x & 7)*160 + (blockIdx.x >> 3);
  const int n = item >> 7;
  const int rem = item & 127;
  const int tyi = rem >> 3, txi = rem & 7;
  const int h0 = tyi << 3, w0 = txi << 4;
  const unsigned short* yn = yb + (size_t)n*HW*64;
  const int wbase = tid & ~63;

  #pragma unroll
  for (int it = 0; it < 5; ++it) {
    int e = tid + it*256;
    if (e < 1152) {
      int frag = e >> 6, ln = e & 63;
      int kk = frag >> 1, half = frag & 1;
      const unsigned short* src = wb2 + (size_t)(ln & 15)*576 + kk*64
                                  + half*32 + ((ln >> 4) << 3);
      gl_lds16(src, (char*)wt + ((size_t)(it*256 + wbase) << 4));
    }
  }
  const bool interior = (txi >= 1) & (txi <= 6) & (tyi >= 1) & (tyi <= 14);
  if (interior) {
    #pragma unroll
    for (int it = 0; it < 6; ++it) {
      int e = tid + it*256;
      if (e < 1440) {
        int sp = e >> 3, c = e & 7;
        int cs = c ^ (sp & 7);
        int sr = sp / 18, sc = sp - sr*18;
        int gh = h0 + sr - 1, gw = w0 + sc - 1;
        const unsigned short* src = yn + ((size_t)(gh*WW + gw))*64 + (cs << 3);
        gl_lds16(src, (char*)yt + ((size_t)(it*256 + wbase) << 4));
      }
    }
  } else {
    for (int e = tid; e < 1440; e += 256) {
      int sp = e >> 3, c = e & 7;
      int sr = sp / 18, sc = sp - sr*18;
      int gh = h0 + sr - 1, gw = w0 + sc - 1;
      uint4 v = make_uint4(0u,0u,0u,0u);
      if (gh >= 0 && gh < HH && gw >= 0 && gw < WW)
        v = *(const uint4*)(yn + ((size_t)(gh*WW + gw))*64 + (c << 3));
      *(uint4*)(&yt[sp*64 + ((c ^ (sp & 7)) << 3)]) = v;
    }
  }
  __syncthreads();

  f32x4 zero4 = {0.f, 0.f, 0.f, 0.f};
  f32x4 acc[2];
  #pragma unroll
  for (int i = 0; i < 2; ++i) acc[i] = zero4;

  #pragma unroll
  for (int half = 0; half < 2; ++half) {
    short8 bf[4][3];
    #pragma unroll
    for (int rr = 0; rr < 4; ++rr)
      #pragma unroll
      for (int dx = 0; dx < 3; ++dx) {
        int sp = (wave*2 + rr)*18 + (r + dx);
        bf[rr][dx] = *(const short8*)(&yt[sp*64 + ((((half << 2) | q) ^ (sp & 7)) << 3)]);
      }
    #pragma unroll
    for (int kk = 0; kk < 9; ++kk) {
      const int dy = kk / 3, dx = kk - dy*3;
      short8 a = *(const short8*)(&wt[((kk*2 + half) << 9) + (lane << 3)]);
      #pragma unroll
      for (int i = 0; i < 2; ++i)
        acc[i] = __builtin_amdgcn_mfma_f32_16x16x32_bf16(a, bf[i+dy][dx], acc[i], 0, 0, 0);
    }
  }

  #pragma unroll
  for (int i = 0; i < 2; ++i) {
    int py = wave*2 + i;
    #pragma unroll
    for (int t2 = 0; t2 < 4; ++t2) {
      int oc = (q << 2) + t2;
      if (oc < 9)
        ker0[((size_t)n*9 + oc)*HW + (h0+py)*WW + w0 + r] = acc[i][t2] + b2[oc];
    }
  }
}

// ---- dynamic filtering v8 (frozen R13): plane-layout xb reads.
__global__ __launch_bounds__(256) void dynf_k(
    const unsigned short* __restrict__ xb, const float* __restrict__ ker0,
    float* __restrict__ out) {
  __shared__ float xs0[TT*324*4];          // 25920 B
  __shared__ float xs1[TT*324*4];          // 25920 B
  const int tw = threadIdx.x, th = threadIdx.y;
  const int tid = th*16 + tw;
  const int wz = blockIdx.z;
  const int bi = wz >> 2, cio = (wz & 3) << 4;
  const int h0 = blockIdx.y << 4, w0 = blockIdx.x << 4;
  const int pix = (h0+th)*WW + w0 + tw;

  float kv[45]; float s = 0.f;
  #pragma unroll
  for (int t5 = 0; t5 < TT; ++t5)
    #pragma unroll
    for (int kk = 0; kk < 9; ++kk) {
      float v = ker0[((size_t)(bi*TT + t5)*9 + kk)*HW + pix];
      kv[t5*9 + kk] = v; s += v;
    }
  const float m = (s - 1.f) * (1.f/45.f);   // mean - 1/45
  #pragma unroll
  for (int qq = 0; qq < 45; ++qq) kv[qq] -= m;

  for (int co = 0; co < 2; ++co) {
    const int ci0 = cio + (co << 3);
    const int cg = ci0 >> 3;                // plane index 0..7
    __syncthreads();                        // xs consumed by previous round
    for (int e = tid; e < TT*324; e += 256) {
      int t5 = e / 324, sp = e - t5*324;
      int rr = sp / 18, cc = sp - rr*18;
      int gh = min(max(h0 + rr - 1, 0), HH-1);
      int gw = min(max(w0 + cc - 1, 0), WW-1);
      uint4 raw = *(const uint4*)(xb + (((size_t)((bi*TT + t5)*8 + cg))*HW + gh*WW + gw)*8);
      xs0[(e << 2) + 0] = bf2f(raw.x & 0xffffu);
      xs0[(e << 2) + 1] = bf2f(raw.x >> 16);
      xs0[(e << 2) + 2] = bf2f(raw.y & 0xffffu);
      xs0[(e << 2) + 3] = bf2f(raw.y >> 16);
      xs1[(e << 2) + 0] = bf2f(raw.z & 0xffffu);
      xs1[(e << 2) + 1] = bf2f(raw.z >> 16);
      xs1[(e << 2) + 2] = bf2f(raw.w & 0xffffu);
      xs1[(e << 2) + 3] = bf2f(raw.w >> 16);
    }
    __syncthreads();

    #pragma unroll
    for (int p = 0; p < 2; ++p) {
      const float* plane = p ? xs1 : xs0;
      float a0 = 0.f, a1 = 0.f, a2 = 0.f, a3 = 0.f;
      #pragma unroll
      for (int t5 = 0; t5 < TT; ++t5)
        #pragma unroll
        for (int dy = 0; dy < 3; ++dy)
          #pragma unroll
          for (int dx = 0; dx < 3; ++dx) {
            f32x4 xv = *(const f32x4*)(&plane[(t5*324 + (th+dy)*18 + (tw+dx)) << 2]);
            float k = kv[t5*9 + dy*3 + dx];
            a0 = fmaf(xv[0], k, a0); a1 = fmaf(xv[1], k, a1);
            a2 = fmaf(xv[2], k, a2); a3 = fmaf(xv[3], k, a3);
          }
      float* op = out + ((size_t)(bi*CC + ci0 + p*4))*HW + pix;
      op[0] = a0; op[HW] = a1; op[2*(size_t)HW] = a2; op[3*(size_t)HW] = a3;
    }
  }
}

extern "C" void kernel_launch(void* const* d_in, const int* in_sizes, int n_in,
                              void* d_out, int out_size, void* d_ws, size_t ws_size,
                              hipStream_t stream) {
  const float* x  = (const float*)d_in[0];
  const float* w1 = (const float*)d_in[1];
  const float* b1 = (const float*)d_in[2];
  const float* w2 = (const float*)d_in[3];
  const float* b2 = (const float*)d_in[4];
  float* out = (float*)d_out;

  unsigned short* xb  = (unsigned short*)d_ws;
  unsigned short* yb  = xb + (size_t)NI*HW*64;
  float*          ker0 = (float*)(yb + (size_t)NI*HW*64);
  unsigned short* wb1 = (unsigned short*)(ker0 + (size_t)NI*9*HW);
  unsigned short* wb2 = wb1 + 64*576;

  pack_k    <<<NI*HH + 144, 256, 0, stream>>>(x, w1, w2, xb, wb1, wb2);
  conv1_mfma<<<640,  256, 0, stream>>>(xb, wb1, b1, yb);
  conv2_mfma<<<1280, 256, 0, stream>>>(yb, wb2, b2, ker0);
  dynf_k    <<<dim3(8,8,8), dim3(16,16), 0, stream>>>(xb, ker0, out);
}

// Round 12
// 140.488 us; speedup vs baseline: 1.0977x; 1.0977x over previous
//
#include <hip/hip_runtime.h>
#include <hip/hip_bf16.h>

#define HH 128
#define WW 128
#define CC 64
#define TT 5
#define HW (HH*WW)
#define NI 10

typedef __attribute__((ext_vector_type(8))) short short8;
typedef __attribute__((ext_vector_type(4))) float f32x4;

typedef const unsigned int __attribute__((address_space(1))) gu32;
typedef unsigned int __attribute__((address_space(3))) lu32;

__device__ __forceinline__ void gl_lds16(const void* g, void* l) {
  __builtin_amdgcn_global_load_lds((gu32*)g, (lu32*)l, 16, 0, 0);
}

__device__ __forceinline__ float bf2f(unsigned int bits16) {
  union { unsigned int u; float f; } v; v.u = bits16 << 16; return v.f;
}
__device__ __forceinline__ unsigned short f2bf(float f) {
  __hip_bfloat16 h = __float2bfloat16(f);
  return *reinterpret_cast<unsigned short*>(&h);
}

// xb layout: 8-channel planes. Element (n, cg, p, c) at ((n*8+cg)*HW + p)*8 + c.
//
// R24 = revert to R21 (session best, 141.2us). R23's nt hints regressed -12us:
// nt-store yb bypasses L2, so conv2's yb reads all miss — yb is re-read within
// the pipeline, evicting it is wrong. Final state: 4 kernels, XCD-chunked
// grids, conv1 = v10 body (weights-only LDS 36.9KB, 3 blk/CU, x direct from
// L2-resident planes).
// Ceiling record: fixed harness cost ~88us (256MiB re-poison fill 42us +
// reset dispatch train, launch-count-independent per R15); kernel work ~53us
// vs ~40us memory floor; conv1 pinned ~30us across 3 structures, all pipes
// <26% — short-kernel latency floor.

// ---- merged pack (R20: image blocks XCD-swizzled)
__global__ __launch_bounds__(256) void pack_k(const float* __restrict__ x,
    const float* __restrict__ w1, const float* __restrict__ w2,
    unsigned short* __restrict__ xb, unsigned short* __restrict__ wb1,
    unsigned short* __restrict__ wb2) {
  __shared__ unsigned short tb[128*68];
  const int tid = threadIdx.x;
  const int bx = blockIdx.x;
  if (bx >= NI*HH) {
    int idx = (bx - NI*HH)*256 + tid;
    if (idx < 64*576) {
      int oc = idx / 576, rem = idx - oc*576, kk = rem >> 6, ic = rem & 63;
      wb1[idx] = f2bf(w1[(oc*64 + ic)*9 + kk]);
    }
    if (idx < 16*576) {
      int oc = idx / 576, rem = idx - oc*576, kk = rem >> 6, ic = rem & 63;
      wb2[idx] = (oc < 9) ? f2bf(w2[(oc*64 + ic)*9 + kk]) : (unsigned short)0;
    }
    return;
  }
  // 1280 = 8*160; XCD (bx&7) owns items [k*160,(k+1)*160) = 1.25 frames
  const int item = (bx & 7)*160 + (bx >> 3);
  const int n = item >> 7, h = item & 127;
  const int bi = n / 5, ti = n - bi*5;
  const float* xp = x + ((size_t)bi*CC*TT + ti)*HW + (size_t)h*WW;
  for (int e = tid; e < 64*128; e += 256) {
    int ci = e >> 7, w = e & 127;
    tb[w*68 + ci] = f2bf(xp[(size_t)ci*TT*HW + w]);
  }
  __syncthreads();
  for (int e = tid; e < 1024; e += 256) {
    int w = e >> 3, cg = e & 7;
    uint2 lo = *(const uint2*)(&tb[w*68 + cg*8]);
    uint2 hi = *(const uint2*)(&tb[w*68 + cg*8 + 4]);
    uint4 v; v.x = lo.x; v.y = lo.y; v.z = hi.x; v.w = hi.y;
    *(uint4*)(xb + (((size_t)(n*8 + cg))*HW + (size_t)h*WW + w)*8) = v;
  }
}

// ---- conv1 v11: weights in LDS (single 32-oc group buffer), x direct from
// global planes, XCD-chunked 1D grid of 640.
#define STAGE_W1(OCBASE) do {                                               \
    _Pragma("unroll")                                                       \
    for (int it = 0; it < 9; ++it) {                                        \
      int e = tid + it*256;                                                 \
      int frag = e >> 6, ln = e & 63;                                       \
      int kk = frag >> 2, rem2 = frag & 3, half = rem2 >> 1, g = rem2 & 1;  \
      const unsigned short* src = wb1 + (size_t)((OCBASE) + g*16 + (ln & 15))*576 \
                                  + kk*64 + half*32 + ((ln >> 4) << 3);     \
      gl_lds16(src, (char*)wt + ((size_t)(it*256 + wbase) << 4));           \
    }                                                                       \
  } while (0)

__global__ __launch_bounds__(256, 3) void conv1_mfma(
    const unsigned short* __restrict__ xb, const unsigned short* __restrict__ wb1,
    const float* __restrict__ b1, unsigned short* __restrict__ yb) {
  __shared__ unsigned short wt[36*512];   // 36864 B
  const int tid = threadIdx.x;
  const int wave = tid >> 6, lane = tid & 63, q = lane >> 4, r = lane & 15;
  // 640 = 8*80; XCD (gid&7) owns items [k*80,(k+1)*80) = 1.25 frames
  const int item = (blockIdx.x & 7)*80 + (blockIdx.x >> 3);
  const int n = item >> 6;
  const int rem = item & 63;
  const int tyi = rem >> 3, txi = rem & 7;
  const int h0 = tyi << 4, w0 = txi << 4;
  const int wbase = tid & ~63;
  const bool interior = (txi >= 1) & (txi <= 6) & (tyi >= 1) & (tyi <= 6);

  STAGE_W1(0);
  __syncthreads();

  f32x4 zero4 = {0.f, 0.f, 0.f, 0.f};

  #pragma unroll
  for (int g2 = 0; g2 < 2; ++g2) {
    f32x4 acc[4][2];
    #pragma unroll
    for (int i = 0; i < 4; ++i)
      #pragma unroll
      for (int g = 0; g < 2; ++g) acc[i][g] = zero4;

    #pragma unroll
    for (int half = 0; half < 2; ++half) {
      short8 bf[6][3];
      if (interior) {
        #pragma unroll
        for (int rr = 0; rr < 6; ++rr) {
          const int gh = h0 + (wave << 2) + rr - 1;
          #pragma unroll
          for (int dx = 0; dx < 3; ++dx) {
            const int gw = w0 + r + dx - 1;
            const int cg = (half << 2) | q;
            bf[rr][dx] = *(const short8*)(xb +
                (((size_t)((n << 3) + cg))*HW + gh*WW + gw)*8);
          }
        }
      } else {
        #pragma unroll
        for (int rr = 0; rr < 6; ++rr) {
          const int gh = h0 + (wave << 2) + rr - 1;
          #pragma unroll
          for (int dx = 0; dx < 3; ++dx) {
            const int gw = w0 + r + dx - 1;
            const int cg = (half << 2) | q;
            const bool ok = ((unsigned)gh < (unsigned)HH) &
                            ((unsigned)gw < (unsigned)WW);
            const size_t off = ok ? (size_t)(gh*WW + gw) : (size_t)0;
            uint4 v = *(const uint4*)(xb +
                (((size_t)((n << 3) + cg))*HW + off)*8);
            if (!ok) v = make_uint4(0u, 0u, 0u, 0u);
            bf[rr][dx] = *reinterpret_cast<short8*>(&v);
          }
        }
      }
      #pragma unroll
      for (int kk = 0; kk < 9; ++kk) {
        const int dy = kk / 3, dx = kk - dy*3;
        short8 a0 = *(const short8*)(&wt[((kk*4 + half*2 + 0) << 9) + (lane << 3)]);
        short8 a1 = *(const short8*)(&wt[((kk*4 + half*2 + 1) << 9) + (lane << 3)]);
        #pragma unroll
        for (int i = 0; i < 4; ++i) {
          acc[i][0] = __builtin_amdgcn_mfma_f32_16x16x32_bf16(a0, bf[i+dy][dx], acc[i][0], 0, 0, 0);
          acc[i][1] = __builtin_amdgcn_mfma_f32_16x16x32_bf16(a1, bf[i+dy][dx], acc[i][1], 0, 0, 0);
        }
      }
    }

    if (g2 == 0) {
      __syncthreads();      // all waves done reading wt(group 0)
      STAGE_W1(32);         // stage oc 32..63; latency hidden under y-stores
    }

    #pragma unroll
    for (int i = 0; i < 4; ++i) {
      int py = wave*4 + i;
      unsigned short* yp = yb + ((size_t)n*HW + (h0+py)*WW + (w0+r))*64;
      #pragma unroll
      for (int g = 0; g < 2; ++g) {
        int oc0 = (g2 << 5) + g*16 + (q << 2);
        f32x4 bias = *(const f32x4*)(b1 + oc0);
        float v0 = acc[i][g][0] + bias[0]; v0 = (v0 >= 0.f) ? v0 : 0.2f*v0;
        float v1 = acc[i][g][1] + bias[1]; v1 = (v1 >= 0.f) ? v1 : 0.2f*v1;
        float v2 = acc[i][g][2] + bias[2]; v2 = (v2 >= 0.f) ? v2 : 0.2f*v2;
        float v3 = acc[i][g][3] + bias[3]; v3 = (v3 >= 0.f) ? v3 : 0.2f*v3;
        uint2 pk;
        pk.x = (unsigned int)f2bf(v0) | ((unsigned int)f2bf(v1) << 16);
        pk.y = (unsigned int)f2bf(v2) | ((unsigned int)f2bf(v3) << 16);
        *(uint2*)(yp + oc0) = pk;
      }
    }

    if (g2 == 0) __syncthreads();   // wt(group 1) landed
  }
}

// ---- conv2 v7 (R20: XCD-swizzled 1D grid of 1280)
__global__ __launch_bounds__(256) void conv2_mfma(
    const unsigned short* __restrict__ yb, const unsigned short* __restrict__ wb2,
    const float* __restrict__ b2, float* __restrict__ ker0) {
  __shared__ unsigned short yt[180*64];
  __shared__ unsigned short wt[18*512];
  const int tid = threadIdx.x;
  const int wave = tid >> 6, lane = tid & 63, q = lane >> 4, r = lane & 15;
  const int item = (blockIdx.x & 7)*160 + (blockIdx.x >> 3);
  const int n = item >> 7;
  const int rem = item & 127;
  const int tyi = rem >> 3, txi = rem & 7;
  const int h0 = tyi << 3, w0 = txi << 4;
  const unsigned short* yn = yb + (size_t)n*HW*64;
  const int wbase = tid & ~63;

  #pragma unroll
  for (int it = 0; it < 5; ++it) {
    int e = tid + it*256;
    if (e < 1152) {
      int frag = e >> 6, ln = e & 63;
      int kk = frag >> 1, half = frag & 1;
      const unsigned short* src = wb2 + (size_t)(ln & 15)*576 + kk*64
                                  + half*32 + ((ln >> 4) << 3);
      gl_lds16(src, (char*)wt + ((size_t)(it*256 + wbase) << 4));
    }
  }
  const bool interior = (txi >= 1) & (txi <= 6) & (tyi >= 1) & (tyi <= 14);
  if (interior) {
    #pragma unroll
    for (int it = 0; it < 6; ++it) {
      int e = tid + it*256;
      if (e < 1440) {
        int sp = e >> 3, c = e & 7;
        int cs = c ^ (sp & 7);
        int sr = sp / 18, sc = sp - sr*18;
        int gh = h0 + sr - 1, gw = w0 + sc - 1;
        const unsigned short* src = yn + ((size_t)(gh*WW + gw))*64 + (cs << 3);
        gl_lds16(src, (char*)yt + ((size_t)(it*256 + wbase) << 4));
      }
    }
  } else {
    for (int e = tid; e < 1440; e += 256) {
      int sp = e >> 3, c = e & 7;
      int sr = sp / 18, sc = sp - sr*18;
      int gh = h0 + sr - 1, gw = w0 + sc - 1;
      uint4 v = make_uint4(0u,0u,0u,0u);
      if (gh >= 0 && gh < HH && gw >= 0 && gw < WW)
        v = *(const uint4*)(yn + ((size_t)(gh*WW + gw))*64 + (c << 3));
      *(uint4*)(&yt[sp*64 + ((c ^ (sp & 7)) << 3)]) = v;
    }
  }
  __syncthreads();

  f32x4 zero4 = {0.f, 0.f, 0.f, 0.f};
  f32x4 acc[2];
  #pragma unroll
  for (int i = 0; i < 2; ++i) acc[i] = zero4;

  #pragma unroll
  for (int half = 0; half < 2; ++half) {
    short8 bf[4][3];
    #pragma unroll
    for (int rr = 0; rr < 4; ++rr)
      #pragma unroll
      for (int dx = 0; dx < 3; ++dx) {
        int sp = (wave*2 + rr)*18 + (r + dx);
        bf[rr][dx] = *(const short8*)(&yt[sp*64 + ((((half << 2) | q) ^ (sp & 7)) << 3)]);
      }
    #pragma unroll
    for (int kk = 0; kk < 9; ++kk) {
      const int dy = kk / 3, dx = kk - dy*3;
      short8 a = *(const short8*)(&wt[((kk*2 + half) << 9) + (lane << 3)]);
      #pragma unroll
      for (int i = 0; i < 2; ++i)
        acc[i] = __builtin_amdgcn_mfma_f32_16x16x32_bf16(a, bf[i+dy][dx], acc[i], 0, 0, 0);
    }
  }

  #pragma unroll
  for (int i = 0; i < 2; ++i) {
    int py = wave*2 + i;
    #pragma unroll
    for (int t2 = 0; t2 < 4; ++t2) {
      int oc = (q << 2) + t2;
      if (oc < 9)
        ker0[((size_t)n*9 + oc)*HW + (h0+py)*WW + w0 + r] = acc[i][t2] + b2[oc];
    }
  }
}

// ---- dynamic filtering v8 (frozen R13): plane-layout xb reads.
__global__ __launch_bounds__(256) void dynf_k(
    const unsigned short* __restrict__ xb, const float* __restrict__ ker0,
    float* __restrict__ out) {
  __shared__ float xs0[TT*324*4];          // 25920 B
  __shared__ float xs1[TT*324*4];          // 25920 B
  const int tw = threadIdx.x, th = threadIdx.y;
  const int tid = th*16 + tw;
  const int wz = blockIdx.z;
  const int bi = wz >> 2, cio = (wz & 3) << 4;
  const int h0 = blockIdx.y << 4, w0 = blockIdx.x << 4;
  const int pix = (h0+th)*WW + w0 + tw;

  float kv[45]; float s = 0.f;
  #pragma unroll
  for (int t5 = 0; t5 < TT; ++t5)
    #pragma unroll
    for (int kk = 0; kk < 9; ++kk) {
      float v = ker0[((size_t)(bi*TT + t5)*9 + kk)*HW + pix];
      kv[t5*9 + kk] = v; s += v;
    }
  const float m = (s - 1.f) * (1.f/45.f);   // mean - 1/45
  #pragma unroll
  for (int qq = 0; qq < 45; ++qq) kv[qq] -= m;

  for (int co = 0; co < 2; ++co) {
    const int ci0 = cio + (co << 3);
    const int cg = ci0 >> 3;                // plane index 0..7
    __syncthreads();                        // xs consumed by previous round
    for (int e = tid; e < TT*324; e += 256) {
      int t5 = e / 324, sp = e - t5*324;
      int rr = sp / 18, cc = sp - rr*18;
      int gh = min(max(h0 + rr - 1, 0), HH-1);
      int gw = min(max(w0 + cc - 1, 0), WW-1);
      uint4 raw = *(const uint4*)(xb + (((size_t)((bi*TT + t5)*8 + cg))*HW + gh*WW + gw)*8);
      xs0[(e << 2) + 0] = bf2f(raw.x & 0xffffu);
      xs0[(e << 2) + 1] = bf2f(raw.x >> 16);
      xs0[(e << 2) + 2] = bf2f(raw.y & 0xffffu);
      xs0[(e << 2) + 3] = bf2f(raw.y >> 16);
      xs1[(e << 2) + 0] = bf2f(raw.z & 0xffffu);
      xs1[(e << 2) + 1] = bf2f(raw.z >> 16);
      xs1[(e << 2) + 2] = bf2f(raw.w & 0xffffu);
      xs1[(e << 2) + 3] = bf2f(raw.w >> 16);
    }
    __syncthreads();

    #pragma unroll
    for (int p = 0; p < 2; ++p) {
      const float* plane = p ? xs1 : xs0;
      float a0 = 0.f, a1 = 0.f, a2 = 0.f, a3 = 0.f;
      #pragma unroll
      for (int t5 = 0; t5 < TT; ++t5)
        #pragma unroll
        for (int dy = 0; dy < 3; ++dy)
          #pragma unroll
          for (int dx = 0; dx < 3; ++dx) {
            f32x4 xv = *(const f32x4*)(&plane[(t5*324 + (th+dy)*18 + (tw+dx)) << 2]);
            float k = kv[t5*9 + dy*3 + dx];
            a0 = fmaf(xv[0], k, a0); a1 = fmaf(xv[1], k, a1);
            a2 = fmaf(xv[2], k, a2); a3 = fmaf(xv[3], k, a3);
          }
      float* op = out + ((size_t)(bi*CC + ci0 + p*4))*HW + pix;
      op[0] = a0; op[HW] = a1; op[2*(size_t)HW] = a2; op[3*(size_t)HW] = a3;
    }
  }
}

extern "C" void kernel_launch(void* const* d_in, const int* in_sizes, int n_in,
                              void* d_out, int out_size, void* d_ws, size_t ws_size,
                              hipStream_t stream) {
  const float* x  = (const float*)d_in[0];
  const float* w1 = (const float*)d_in[1];
  const float* b1 = (const float*)d_in[2];
  const float* w2 = (const float*)d_in[3];
  const float* b2 = (const float*)d_in[4];
  float* out = (float*)d_out;

  unsigned short* xb  = (unsigned short*)d_ws;
  unsigned short* yb  = xb + (size_t)NI*HW*64;
  float*          ker0 = (float*)(yb + (size_t)NI*HW*64);
  unsigned short* wb1 = (unsigned short*)(ker0 + (size_t)NI*9*HW);
  unsigned short* wb2 = wb1 + 64*576;

  pack_k    <<<NI*HH + 144, 256, 0, stream>>>(x, w1, w2, xb, wb1, wb2);
  conv1_mfma<<<640,  256, 0, stream>>>(xb, wb1, b1, yb);
  conv2_mfma<<<1280, 256, 0, stream>>>(yb, wb2, b2, ker0);
  dynf_k    <<<dim3(8,8,8), dim3(16,16), 0, stream>>>(xb, ker0, out);
}